// Round 8
// baseline (188.745 us; speedup 1.0000x reference)
//
#include <hip/hip_runtime.h>
#include <hip/hip_bf16.h>

#define L_    4096
#define DIN   512
#define DOUT  256
#define NH    4
#define HD    64
#define JW    128                      // L_/32 j-words per row

typedef unsigned short u16;
typedef __attribute__((ext_vector_type(8))) short short8;   // 8 x bf16
typedef __attribute__((ext_vector_type(4))) float floatx4;  // MFMA C/D frag

__device__ __forceinline__ float bf2f(u16 u) {
  union { unsigned u32; float f; } v; v.u32 = ((unsigned)u) << 16; return v.f;
}
__device__ __forceinline__ u16 f2bf(float f) {  // RNE
  union { float f; unsigned u; } v; v.f = f;
  unsigned r = v.u + 0x7fff + ((v.u >> 16) & 1);
  return (u16)(r >> 16);
}
__device__ __forceinline__ unsigned cvt2(float a, float b) {  // HW pack fp32x2->bf16x2
  __hip_bfloat162 v = __float22bfloat162_rn(make_float2(a, b));
  return *reinterpret_cast<unsigned*>(&v);
}
__device__ __forceinline__ short8 pack8(const float* __restrict__ p) {
  float4 a = *(const float4*)p, b = *(const float4*)(p + 4);
  union { unsigned u[4]; short8 s; } r;
  r.u[0] = cvt2(a.x, a.y); r.u[1] = cvt2(a.z, a.w);
  r.u[2] = cvt2(b.x, b.y); r.u[3] = cvt2(b.z, b.w);
  return r.s;
}

// C/D map discovery (r10-verified contract); layout-map-free probes.
__device__ __forceinline__ void mfma_cdmap(int lane, int* rowm, int* colm) {
  const int c0 = lane & 15;
  union { u16 u[8]; short8 s; } a1, b1, a2, b2;
  const u16 one = f2bf(1.f), cid = f2bf((float)c0);
  #pragma unroll
  for (int j = 0; j < 8; ++j) { a1.u[j] = cid; b1.u[j] = one; a2.u[j] = one; b2.u[j] = cid; }
  floatx4 z = {0.f, 0.f, 0.f, 0.f};
  floatx4 dr = __builtin_amdgcn_mfma_f32_16x16x32_bf16(a1.s, b1.s, z, 0, 0, 0);
  floatx4 dc = __builtin_amdgcn_mfma_f32_16x16x32_bf16(a2.s, b2.s, z, 0, 0, 0);
  #pragma unroll
  for (int r = 0; r < 4; ++r) {
    rowm[r] = (int)(dr[r] * 0.03125f + 0.5f);
    colm[r] = (int)(dc[r] * 0.03125f + 0.5f);
  }
}

// ---------------------------------------------------------------------------
// k_ab: A (64 MB) -> Abits (2 MB bitmask)  [all 2048 blocks]
//       + W -> Wf bf16 fragment pack       [blocks 0..15]
//       + zero the 512 pair-flags          [block 0]
// ---------------------------------------------------------------------------
__global__ __launch_bounds__(256) void k_ab(const int* __restrict__ A,
                                            unsigned* __restrict__ Abits,
                                            const float* __restrict__ W,
                                            u16* __restrict__ Wf,
                                            int* flags) {
  const int t = threadIdx.x;
  const int g = blockIdx.x * 256 + t;   // 524288 threads
  const int lane = t & 63;
  #pragma unroll
  for (int r = 0; r < 8; ++r) {
    const size_t gi = (size_t)r * 524288 + g;     // int4 index
    int4 v = *(const int4*)(A + gi * 4);
    unsigned nib = (v.x > 0 ? 1u : 0u) | (v.y > 0 ? 2u : 0u)
                 | (v.z > 0 ? 4u : 0u) | (v.w > 0 ? 8u : 0u);
    unsigned part = nib << ((lane & 7) * 4);
    part |= __shfl_xor(part, 1, 64);
    part |= __shfl_xor(part, 2, 64);
    part |= __shfl_xor(part, 4, 64);
    if ((lane & 7) == 0) Abits[gi >> 3] = part;
  }
  if (flags && blockIdx.x == 0) { flags[t] = 0; flags[t + 256] = 0; }
  if (blockIdx.x < 16) {   // W pack (ex-k0b)
    const int col = g >> 4, kblock = g & 15;
    const int cg = col >> 6, nt = (col >> 4) & 3, c0 = col & 15;
    const float* src = W + (size_t)col * DIN + kblock * 32;
    u16* dst = Wf + ((size_t)(cg * 4 + nt) * 16 + kblock) * 512 + c0 * 8;
    #pragma unroll
    for (int q = 0; q < 4; ++q) {
      short8 v = pack8(src + q * 8);
      *(short8*)(dst + q * 128) = v;
    }
  }
}

// ---------------------------------------------------------------------------
// K1: Wh = h @ W.T (r13-verified structure, unchanged).
// ---------------------------------------------------------------------------
__global__ __launch_bounds__(1024) void k1_wh(
    const float* __restrict__ h, const u16* __restrict__ Wf,
    const float* __restrict__ attn,
    u16* __restrict__ WhTf, float* __restrict__ s1g, float2* __restrict__ bdg)
{
  const int i0 = blockIdx.x * 16;
  const int t = threadIdx.x;
  const int wv = t >> 6, lane = t & 63, q = lane >> 4, c0 = lane & 15;
  const int cg = wv & 3, kc = wv >> 2;
  int rowm[4], colm[4];
  mfma_cdmap(lane, rowm, colm);

  __shared__ u16  hT[16][DIN + 8];
  __shared__ float pA[16][DOUT + 8];
  __shared__ float pB[16][DOUT + 8];
  __shared__ float attnL[NH * 128];

  if (t < 512) attnL[t] = attn[t];
  {  // stage h-tile coalesced
    const int row = t >> 6, c8 = (t & 63) * 8;
    const float* hp = h + (size_t)(i0 + row) * DIN + c8;
    float4 a = *(const float4*)hp;
    float4 b = *(const float4*)(hp + 4);
    union { unsigned u[4]; int4 v; } pk;
    pk.u[0] = cvt2(a.x, a.y); pk.u[1] = cvt2(a.z, a.w);
    pk.u[2] = cvt2(b.x, b.y); pk.u[3] = cvt2(b.z, b.w);
    *(int4*)&hT[row][c8] = pk.v;
  }
  __syncthreads();

  floatx4 acc[4] = {};
  #pragma unroll
  for (int ktl = 0; ktl < 4; ++ktl) {
    const int kb = kc * 128 + ktl * 32 + q * 8;
    short8 af = *(const short8*)&hT[c0][kb];        // A[m=c0][k]
    #pragma unroll
    for (int nt = 0; nt < 4; ++nt) {
      short8 bf = *(const short8*)(Wf + ((size_t)(cg * 4 + nt) * 16 + kc * 4 + ktl) * 512 + lane * 8);
      acc[nt] = __builtin_amdgcn_mfma_f32_16x16x32_bf16(af, bf, acc[nt], 0, 0, 0);
    }
  }

  auto writeT = [&](float (*P)[DOUT + 8]) {
    #pragma unroll
    for (int nt = 0; nt < 4; ++nt)
      #pragma unroll
      for (int r = 0; r < 4; ++r)
        P[rowm[r]][cg * 64 + nt * 16 + colm[r]] = acc[nt][r];
  };
  auto addB2A = [&]() {
    const int row = t >> 6, c4 = (t & 63) * 4;
    float4* a = (float4*)&pA[row][c4];
    float4 bv = *(float4*)&pB[row][c4];
    float4 av = *a;
    av.x += bv.x; av.y += bv.y; av.z += bv.z; av.w += bv.w;
    *a = av;
  };

  if (kc == 0) writeT(pA);
  if (kc == 1) writeT(pB);
  __syncthreads();
  addB2A();
  __syncthreads();
  if (kc == 2) writeT(pB);
  __syncthreads();
  addB2A();
  __syncthreads();
  if (kc == 3) writeT(pB);
  __syncthreads();
  addB2A();
  __syncthreads();

  if (t < 64) {  // s1 + factored-exp pair for s2
    const int r = t & 15, hh = t >> 4;
    float s1 = 0.f, s2 = 0.f;
    for (int d = 0; d < HD; ++d) {
      float v = pA[r][hh * 64 + d];
      s1 += v * attnL[hh * 128 + d];
      s2 += v * attnL[hh * 128 + 64 + d];
    }
    s1g[hh * L_ + i0 + r] = s1;
    bdg[hh * L_ + i0 + r] = make_float2(__expf(s2), __expf(0.2f * s2));
  }

  if (t < 256) {  // WhTf store: thread t = d; two 16B writes
    const int d = t;
    const int hd = d >> 6, nt = (d >> 4) & 3, dc0 = d & 15;
    const int jblock = i0 >> 5, qbase = (i0 & 31) >> 3;
    u16* base = WhTf + ((size_t)(hd * 4 + nt) * JW + jblock) * 512 + dc0 * 8;
    #pragma unroll
    for (int jh = 0; jh < 2; ++jh) {
      const int i = jh * 8;
      union { unsigned u[4]; int4 v; } pk;
      pk.u[0] = cvt2(pA[i + 0][d], pA[i + 1][d]);
      pk.u[1] = cvt2(pA[i + 2][d], pA[i + 3][d]);
      pk.u[2] = cvt2(pA[i + 4][d], pA[i + 5][d]);
      pk.u[3] = cvt2(pA[i + 6][d], pA[i + 7][d]);
      *(int4*)(base + (qbase + jh) * 128) = pk.v;
    }
  }
}

// ---------------------------------------------------------------------------
// K2: masked softmax + PV + fused projection.  Template JS:
//   JS=1: grid 256, full j per block (R3-verified path, fallback).
//   JS=2: grid 512, j-half per block. NO min-waves clamp (R7 failure:
//         (1024,8) -> VGPR 32 -> load serialization + scratch). Natural
//         VGPR ~56 <= 64 => 2 blocks/CU at runtime (8 waves/EU x 56 = 448
//         <= 512 VGPR; 2 x 49 KB <= 160 KB LDS). Partner blocks (2b,2b+1)
//         combine via last-finisher flag protocol (R7-verified correct).
// ---------------------------------------------------------------------------
template<int JS>
__global__ __launch_bounds__(1024) void k2_attn(
    const unsigned* __restrict__ Abits, const u16* __restrict__ WhTf,
    const float* __restrict__ s1g, const float2* __restrict__ bdg,
    const float* __restrict__ out_w, const float* __restrict__ out_b,
    float* __restrict__ out,
    float* __restrict__ partNum, float* __restrict__ partDen, int* flags)
{
  constexpr int JWH = JW / JS;        // j-words per row this block: 128 | 64
  constexpr int KT  = 32 / JS;        // kt per jc-chunk: 32 | 16
  const int bid = blockIdx.x;
  const int jh   = (JS == 2) ? (bid & 1) : 0;
  const int tile = (JS == 2) ? (bid >> 1) : bid;
  const int i0 = tile * 16;
  const int t = threadIdx.x;
  const int wv = t >> 6, lane = t & 63, q = lane >> 4, c0 = lane & 15;
  const int hd = wv & 3, jc = wv >> 2;

  __shared__ float pA[NH][16][HD + 4];
  __shared__ float pB[NH][16][HD + 4];
  __shared__ float dden[NH][4][16];
  __shared__ float rcpS[NH][16];      // JS=1: rcp; JS=2: raw den, then rcp
  __shared__ u16  CnL[16][DOUT + 8];
  __shared__ unsigned AbitL[16][JWH + 2];
  __shared__ int oldv;

  {  // prologue: stage this block's share of the bitmask (coalesced)
    const int row = t >> 6, l = t & 63;
    if (JS == 1) {
      uint2 w2 = *(const uint2*)&Abits[(size_t)(i0 + row) * JW + l * 2];
      AbitL[row][l * 2] = w2.x;
      AbitL[row][l * 2 + 1] = w2.y;
    } else {
      AbitL[row][l] = Abits[(size_t)(i0 + row) * JW + jh * JWH + l];
    }
  }
  int rowm[4], colm[4];
  mfma_cdmap(lane, rowm, colm);
  __syncthreads();

  const float s1v = s1g[hd * L_ + i0 + c0];
  const float av = __expf(s1v);          // exp(s1)
  const float cv = __expf(0.2f * s1v);   // exp(0.2*s1)
  const float th = __expf(-s1v);         // b >= th  <=>  s1+s2 >= 0
  const int jblk0 = jh * JWH;            // first j-word of this block
  const float2* bdh = bdg + (size_t)hd * L_ + jblk0 * 32 + jc * (1024 / JS);
  const u16* Wc = WhTf + ((size_t)(hd * 4) * JW + jblk0 + jc * KT) * 512 + lane * 8;

  union PF { unsigned u[4]; short8 s; };
  floatx4 acc[4] = {};
  float dpart = 0.f;

  #pragma unroll 1
  for (int kt = 0; kt < KT; ++kt) {
    const float2* p = bdh + kt * 32 + q * 8;
    float4 v0 = *(const float4*)p;       float4 v1 = *(const float4*)(p + 2);
    float4 v2 = *(const float4*)(p + 4); float4 v3 = *(const float4*)(p + 6);
    short8 w[4];
    #pragma unroll
    for (int nt = 0; nt < 4; ++nt)
      w[nt] = *(const short8*)(Wc + ((size_t)nt * JW + kt) * 512);
    const unsigned mb = (AbitL[c0][jc * KT + kt] >> (q * 8)) & 0xffu;
    const float bb[8] = {v0.x, v0.z, v1.x, v1.z, v2.x, v2.z, v3.x, v3.z};
    const float dd[8] = {v0.y, v0.w, v1.y, v1.w, v2.y, v2.w, v3.y, v3.w};
    float ex[8];
    #pragma unroll
    for (int jj = 0; jj < 8; ++jj) {
      float pp = (bb[jj] >= th) ? (av * bb[jj]) : (cv * dd[jj]);
      ex[jj] = ((mb >> jj) & 1u) ? pp : 0.f;
      dpart += ex[jj];
    }
    PF pf;
    pf.u[0] = cvt2(ex[0], ex[1]); pf.u[1] = cvt2(ex[2], ex[3]);
    pf.u[2] = cvt2(ex[4], ex[5]); pf.u[3] = cvt2(ex[6], ex[7]);
    #pragma unroll
    for (int nt = 0; nt < 4; ++nt)
      acc[nt] = __builtin_amdgcn_mfma_f32_16x16x32_bf16(pf.s, w[nt], acc[nt], 0, 0, 0);
  }

  // partial denom of row c0 over this j-chunk
  dpart += __shfl_xor(dpart, 16, 64);
  dpart += __shfl_xor(dpart, 32, 64);
  if (lane < 16) dden[hd][jc][lane] = dpart;

  auto writeT = [&](float (*P)[HD + 4]) {
    #pragma unroll
    for (int nt = 0; nt < 4; ++nt)
      #pragma unroll
      for (int r = 0; r < 4; ++r)
        P[rowm[r]][nt * 16 + colm[r]] = acc[nt][r];
  };
  auto addB2A = [&]() {
    const int h2 = t >> 8, rem = t & 255, row = rem >> 4, d4 = (rem & 15) * 4;
    float4* a = (float4*)&pA[h2][row][d4];
    float4 bv = *(float4*)&pB[h2][row][d4];
    float4 av2 = *a;
    av2.x += bv.x; av2.y += bv.y; av2.z += bv.z; av2.w += bv.w;
    *a = av2;
  };

  if (jc == 0) writeT(pA[hd]);
  if (jc == 1) writeT(pB[hd]);
  __syncthreads();
  if (t < 64) {
    const int hh = t >> 4, r = t & 15;
    float den = dden[hh][0][r] + dden[hh][1][r] + dden[hh][2][r] + dden[hh][3][r];
    rcpS[hh][r] = (JS == 1) ? ((den > 0.f) ? (1.f / den) : 0.f) : den;
  }
  addB2A();
  __syncthreads();
  if (jc == 2) writeT(pB[hd]);
  __syncthreads();
  addB2A();
  __syncthreads();
  if (jc == 3) writeT(pB[hd]);
  __syncthreads();
  addB2A();
  __syncthreads();
  // pA[hh][row][d] = (partial) numerator; rcpS = rcp (JS=1) or raw den (JS=2)

  if (JS == 2) {  // ---- pair combine: last finisher does the tail ----
    if (t == 0)
      oldv = __hip_atomic_fetch_add(&flags[tile], 1, __ATOMIC_ACQ_REL,
                                    __HIP_MEMORY_SCOPE_AGENT);
    __syncthreads();
    const int row = t >> 6, c4 = (t & 63) * 4;
    const int hh = c4 >> 6, d = c4 & 63;
    float* pslot = partNum + ((size_t)tile * 16 + row) * 256 + c4;
    if (oldv == 0) {  // writer: dump partial, signal, exit
      *(float4*)pslot = *(const float4*)&pA[hh][row][d];
      if (t < 64) partDen[tile * 64 + t] = rcpS[t >> 4][t & 15];
      __syncthreads();  // all stores drained (barrier waits vmcnt 0)
      if (t == 0)
        __hip_atomic_store(&flags[256 + tile], 1, __ATOMIC_RELEASE,
                           __HIP_MEMORY_SCOPE_AGENT);
      return;
    }
    // reader: wait for partner, combine
    if (t == 0) {
      while (__hip_atomic_load(&flags[256 + tile], __ATOMIC_ACQUIRE,
                               __HIP_MEMORY_SCOPE_AGENT) == 0)
        __builtin_amdgcn_s_sleep(1);
    }
    __syncthreads();
    {
      float4 o = *(const float4*)pslot;
      float4* a = (float4*)&pA[hh][row][d];
      float4 av2 = *a;
      av2.x += o.x; av2.y += o.y; av2.z += o.z; av2.w += o.w;
      *a = av2;
    }
    if (t < 64) {
      float den = rcpS[t >> 4][t & 15] + partDen[tile * 64 + t];
      rcpS[t >> 4][t & 15] = (den > 0.f) ? (1.f / den) : 0.f;
    }
    __syncthreads();
  }

  {  // Cn (bf16)
    const int row = t >> 6, c4 = (t & 63) * 4;
    #pragma unroll
    for (int x = 0; x < 4; ++x) {
      const int col = c4 + x;
      const int hh = col >> 6, d = col & 63;
      CnL[row][col] = f2bf(pA[hh][row][d] * rcpS[hh][row]);
    }
  }
  __syncthreads();

  if (wv < 4) {  // projection: Out2(16x256) = Cn @ out_w.T
    const int cg = wv;
    floatx4 o[4] = {};
    #pragma unroll
    for (int kt = 0; kt < DOUT / 32; ++kt) {
      const int kb2 = kt * 32 + q * 8;
      short8 afr = *(const short8*)(&CnL[c0][kb2]);
      #pragma unroll
      for (int nt = 0; nt < 4; ++nt) {
        const int col = cg * 64 + nt * 16 + c0;
        short8 bfo = pack8(out_w + (size_t)col * DOUT + kb2);
        o[nt] = __builtin_amdgcn_mfma_f32_16x16x32_bf16(afr, bfo, o[nt], 0, 0, 0);
      }
    }
    #pragma unroll
    for (int nt = 0; nt < 4; ++nt)
      #pragma unroll
      for (int r = 0; r < 4; ++r) {
        const int col = cg * 64 + nt * 16 + colm[r];
        out[(size_t)(i0 + rowm[r]) * DOUT + col] = o[nt][r] + out_b[col];
      }
  }
}

// ---------------------------------------------------------------------------
extern "C" void kernel_launch(void* const* d_in, const int* in_sizes, int n_in,
                              void* d_out, int out_size, void* d_ws, size_t ws_size,
                              hipStream_t stream) {
  const float* h     = (const float*)d_in[0];   // (4096, 512) fp32
  const int*   A     = (const int*)d_in[1];     // (4096, 4096) int32
  const float* W     = (const float*)d_in[2];   // (256, 512) fp32
  const float* attn  = (const float*)d_in[3];   // (4, 128) fp32
  const float* out_w = (const float*)d_in[4];   // (256, 256) fp32
  const float* out_b = (const float*)d_in[5];   // (256,) fp32
  float* outp = (float*)d_out;                  // (4096, 256) fp32

  // ws: WhTf 2MB | s1 64KB | bd 128KB | Abits 2MB | partNum 4MB | partDen 64KB | flags 2KB
  const size_t WHTF_B  = (size_t)DOUT * L_ * 2;          // 2097152
  const size_t S1_B    = (size_t)NH * L_ * 4;            // 65536
  const size_t BD_B    = (size_t)NH * L_ * 8;            // 131072
  const size_t ABITS_B = (size_t)L_ * JW * 4;            // 2097152
  const size_t AB_OFF  = WHTF_B + S1_B + BD_B;
  const size_t PN_OFF  = AB_OFF + ABITS_B;
  const size_t PN_B    = (size_t)256 * 16 * 256 * 4;     // 4 MB
  const size_t PD_B    = (size_t)256 * 64 * 4;           // 64 KB
  const size_t FL_B    = 512 * 4;
  const size_t TOTAL   = PN_OFF + PN_B + PD_B + FL_B;    // ~8.55 MB

  u16*    WhTf = (u16*)d_ws;
  float*  s1g  = (float*)((char*)d_ws + WHTF_B);
  float2* bdg  = (float2*)((char*)d_ws + WHTF_B + S1_B);
  const bool split = (ws_size >= TOTAL);
  // Abits: prefer ws; fall back to the second 2 MB of d_out (non-split only)
  unsigned* Abits = (ws_size >= PN_OFF)
                  ? (unsigned*)((char*)d_ws + AB_OFF)
                  : (unsigned*)((char*)d_out + 2097152);
  float* partNum = (float*)((char*)d_ws + PN_OFF);
  float* partDen = (float*)((char*)d_ws + PN_OFF + PN_B);
  int*   flags   = (int*)((char*)d_ws + PN_OFF + PN_B + PD_B);
  u16* Wf = (u16*)d_out;   // k_ab -> k1 -> k2 serialize; k2 overwrites d_out last

  hipLaunchKernelGGL(k_ab, dim3(2048), dim3(256), 0, stream,
                     A, Abits, W, Wf, split ? flags : (int*)nullptr);
  hipLaunchKernelGGL(k1_wh, dim3(L_ / 16), dim3(1024), 0, stream,
                     h, Wf, attn, WhTf, s1g, bdg);
  if (split) {
    hipLaunchKernelGGL((k2_attn<2>), dim3(L_ / 16 * 2), dim3(1024), 0, stream,
                       Abits, WhTf, s1g, bdg, out_w, out_b, outp,
                       partNum, partDen, flags);
  } else {
    hipLaunchKernelGGL((k2_attn<1>), dim3(L_ / 16), dim3(1024), 0, stream,
                       Abits, WhTf, s1g, bdg, out_w, out_b, outp,
                       partNum, partDen, flags);
  }
}

// Round 9
// 158.771 us; speedup vs baseline: 1.1888x; 1.1888x over previous
//
#include <hip/hip_runtime.h>
#include <hip/hip_bf16.h>

#define L_    4096
#define DIN   512
#define DOUT  256
#define NH    4
#define HD    64
#define JW    128                      // L_/32 j-words per row

typedef unsigned short u16;
typedef __attribute__((ext_vector_type(8))) short short8;   // 8 x bf16
typedef __attribute__((ext_vector_type(4))) float floatx4;  // MFMA C/D frag

__device__ __forceinline__ float bf2f(u16 u) {
  union { unsigned u32; float f; } v; v.u32 = ((unsigned)u) << 16; return v.f;
}
__device__ __forceinline__ u16 f2bf(float f) {  // RNE
  union { float f; unsigned u; } v; v.f = f;
  unsigned r = v.u + 0x7fff + ((v.u >> 16) & 1);
  return (u16)(r >> 16);
}
__device__ __forceinline__ unsigned cvt2(float a, float b) {  // HW pack fp32x2->bf16x2
  __hip_bfloat162 v = __float22bfloat162_rn(make_float2(a, b));
  return *reinterpret_cast<unsigned*>(&v);
}
__device__ __forceinline__ short8 pack8(const float* __restrict__ p) {
  float4 a = *(const float4*)p, b = *(const float4*)(p + 4);
  union { unsigned u[4]; short8 s; } r;
  r.u[0] = cvt2(a.x, a.y); r.u[1] = cvt2(a.z, a.w);
  r.u[2] = cvt2(b.x, b.y); r.u[3] = cvt2(b.z, b.w);
  return r.s;
}

// C/D map discovery (r10-verified contract); layout-map-free probes.
__device__ __forceinline__ void mfma_cdmap(int lane, int* rowm, int* colm) {
  const int c0 = lane & 15;
  union { u16 u[8]; short8 s; } a1, b1, a2, b2;
  const u16 one = f2bf(1.f), cid = f2bf((float)c0);
  #pragma unroll
  for (int j = 0; j < 8; ++j) { a1.u[j] = cid; b1.u[j] = one; a2.u[j] = one; b2.u[j] = cid; }
  floatx4 z = {0.f, 0.f, 0.f, 0.f};
  floatx4 dr = __builtin_amdgcn_mfma_f32_16x16x32_bf16(a1.s, b1.s, z, 0, 0, 0);
  floatx4 dc = __builtin_amdgcn_mfma_f32_16x16x32_bf16(a2.s, b2.s, z, 0, 0, 0);
  #pragma unroll
  for (int r = 0; r < 4; ++r) {
    rowm[r] = (int)(dr[r] * 0.03125f + 0.5f);
    colm[r] = (int)(dc[r] * 0.03125f + 0.5f);
  }
}

// ---------------------------------------------------------------------------
// k_ab: A (64 MB) -> Abits (2 MB bitmask)  [all 2048 blocks]
//       + W -> Wf bf16 fragment pack       [blocks 0..15]   (R6-verified)
// ---------------------------------------------------------------------------
__global__ __launch_bounds__(256) void k_ab(const int* __restrict__ A,
                                            unsigned* __restrict__ Abits,
                                            const float* __restrict__ W,
                                            u16* __restrict__ Wf) {
  const int t = threadIdx.x;
  const int g = blockIdx.x * 256 + t;   // 524288 threads
  const int lane = t & 63;
  #pragma unroll
  for (int r = 0; r < 8; ++r) {
    const size_t gi = (size_t)r * 524288 + g;     // int4 index
    int4 v = *(const int4*)(A + gi * 4);
    unsigned nib = (v.x > 0 ? 1u : 0u) | (v.y > 0 ? 2u : 0u)
                 | (v.z > 0 ? 4u : 0u) | (v.w > 0 ? 8u : 0u);
    unsigned part = nib << ((lane & 7) * 4);
    part |= __shfl_xor(part, 1, 64);
    part |= __shfl_xor(part, 2, 64);
    part |= __shfl_xor(part, 4, 64);
    if ((lane & 7) == 0) Abits[gi >> 3] = part;
  }
  if (blockIdx.x < 16) {   // W pack (ex-k0b)
    const int col = g >> 4, kblock = g & 15;
    const int cg = col >> 6, nt = (col >> 4) & 3, c0 = col & 15;
    const float* src = W + (size_t)col * DIN + kblock * 32;
    u16* dst = Wf + ((size_t)(cg * 4 + nt) * 16 + kblock) * 512 + c0 * 8;
    #pragma unroll
    for (int q = 0; q < 4; ++q) {
      short8 v = pack8(src + q * 8);
      *(short8*)(dst + q * 128) = v;
    }
  }
}

// ---------------------------------------------------------------------------
// K1: Wh = h @ W.T (r13-verified structure, unchanged).
// ---------------------------------------------------------------------------
__global__ __launch_bounds__(1024) void k1_wh(
    const float* __restrict__ h, const u16* __restrict__ Wf,
    const float* __restrict__ attn,
    u16* __restrict__ WhTf, float* __restrict__ s1g, float2* __restrict__ bdg)
{
  const int i0 = blockIdx.x * 16;
  const int t = threadIdx.x;
  const int wv = t >> 6, lane = t & 63, q = lane >> 4, c0 = lane & 15;
  const int cg = wv & 3, kc = wv >> 2;
  int rowm[4], colm[4];
  mfma_cdmap(lane, rowm, colm);

  __shared__ u16  hT[16][DIN + 8];
  __shared__ float pA[16][DOUT + 8];
  __shared__ float pB[16][DOUT + 8];
  __shared__ float attnL[NH * 128];

  if (t < 512) attnL[t] = attn[t];
  {  // stage h-tile coalesced
    const int row = t >> 6, c8 = (t & 63) * 8;
    const float* hp = h + (size_t)(i0 + row) * DIN + c8;
    float4 a = *(const float4*)hp;
    float4 b = *(const float4*)(hp + 4);
    union { unsigned u[4]; int4 v; } pk;
    pk.u[0] = cvt2(a.x, a.y); pk.u[1] = cvt2(a.z, a.w);
    pk.u[2] = cvt2(b.x, b.y); pk.u[3] = cvt2(b.z, b.w);
    *(int4*)&hT[row][c8] = pk.v;
  }
  __syncthreads();

  floatx4 acc[4] = {};
  #pragma unroll
  for (int ktl = 0; ktl < 4; ++ktl) {
    const int kb = kc * 128 + ktl * 32 + q * 8;
    short8 af = *(const short8*)&hT[c0][kb];        // A[m=c0][k]
    #pragma unroll
    for (int nt = 0; nt < 4; ++nt) {
      short8 bf = *(const short8*)(Wf + ((size_t)(cg * 4 + nt) * 16 + kc * 4 + ktl) * 512 + lane * 8);
      acc[nt] = __builtin_amdgcn_mfma_f32_16x16x32_bf16(af, bf, acc[nt], 0, 0, 0);
    }
  }

  auto writeT = [&](float (*P)[DOUT + 8]) {
    #pragma unroll
    for (int nt = 0; nt < 4; ++nt)
      #pragma unroll
      for (int r = 0; r < 4; ++r)
        P[rowm[r]][cg * 64 + nt * 16 + colm[r]] = acc[nt][r];
  };
  auto addB2A = [&]() {
    const int row = t >> 6, c4 = (t & 63) * 4;
    float4* a = (float4*)&pA[row][c4];
    float4 bv = *(float4*)&pB[row][c4];
    float4 av = *a;
    av.x += bv.x; av.y += bv.y; av.z += bv.z; av.w += bv.w;
    *a = av;
  };

  if (kc == 0) writeT(pA);
  if (kc == 1) writeT(pB);
  __syncthreads();
  addB2A();
  __syncthreads();
  if (kc == 2) writeT(pB);
  __syncthreads();
  addB2A();
  __syncthreads();
  if (kc == 3) writeT(pB);
  __syncthreads();
  addB2A();
  __syncthreads();

  if (t < 64) {  // s1 + factored-exp pair for s2
    const int r = t & 15, hh = t >> 4;
    float s1 = 0.f, s2 = 0.f;
    for (int d = 0; d < HD; ++d) {
      float v = pA[r][hh * 64 + d];
      s1 += v * attnL[hh * 128 + d];
      s2 += v * attnL[hh * 128 + 64 + d];
    }
    s1g[hh * L_ + i0 + r] = s1;
    bdg[hh * L_ + i0 + r] = make_float2(__expf(s2), __expf(0.2f * s2));
  }

  if (t < 256) {  // WhTf store: thread t = d; two 16B writes
    const int d = t;
    const int hd = d >> 6, nt = (d >> 4) & 3, dc0 = d & 15;
    const int jblock = i0 >> 5, qbase = (i0 & 31) >> 3;
    u16* base = WhTf + ((size_t)(hd * 4 + nt) * JW + jblock) * 512 + dc0 * 8;
    #pragma unroll
    for (int jh = 0; jh < 2; ++jh) {
      const int i = jh * 8;
      union { unsigned u[4]; int4 v; } pk;
      pk.u[0] = cvt2(pA[i + 0][d], pA[i + 1][d]);
      pk.u[1] = cvt2(pA[i + 2][d], pA[i + 3][d]);
      pk.u[2] = cvt2(pA[i + 4][d], pA[i + 5][d]);
      pk.u[3] = cvt2(pA[i + 6][d], pA[i + 7][d]);
      *(int4*)(base + (qbase + jh) * 128) = pk.v;
    }
  }
}

// ---------------------------------------------------------------------------
// K2: masked softmax + PV + fused projection. R3-verified structure
// (grid 256, 1024 thr, 16 waves = hd x jc), with a LEAN hot loop:
//  - all 5 address streams strength-reduced to incremented pointers
//    (bd +256B/kt, 4x Wc +1KB/kt, Abit +4B/kt) - no size_t math in loop
//  - ex computed directly from float4 components (no bb[]/dd[] marshal)
//  - tree-sum for dpart
// Rationale: R3's VALUBusy 41% @ 16 waves/CU ~ 190 VALU insts/kt-iter;
// softmax math needs ~60. Occupancy levers are closed (R7/R8: effective
// regs = VGPR+AGPR ~ 84 -> one 16-wave block per CU, hard).
// ---------------------------------------------------------------------------
__global__ __launch_bounds__(1024) void k2_attn(
    const unsigned* __restrict__ Abits, const u16* __restrict__ WhTf,
    const float* __restrict__ s1g, const float2* __restrict__ bdg,
    const float* __restrict__ out_w, const float* __restrict__ out_b,
    float* __restrict__ out)
{
  const int i0 = blockIdx.x * 16;
  const int t = threadIdx.x;
  const int wv = t >> 6, lane = t & 63, q = lane >> 4, c0 = lane & 15;
  const int hd = wv & 3, jc = wv >> 2;

  __shared__ float pA[NH][16][HD + 4];
  __shared__ float pB[NH][16][HD + 4];
  __shared__ float dden[NH][4][16];
  __shared__ float rcpS[NH][16];
  __shared__ u16  CnL[16][DOUT + 8];
  __shared__ unsigned AbitL[16][JW + 2];   // row-stride 130 -> varied banks

  {  // prologue: stage this block's 16 rows of the bitmask (8 KB, coalesced)
    const int row = t >> 6, l = t & 63;
    uint2 w2 = *(const uint2*)&Abits[(size_t)(i0 + row) * JW + l * 2];
    AbitL[row][l * 2] = w2.x;
    AbitL[row][l * 2 + 1] = w2.y;
  }
  int rowm[4], colm[4];
  mfma_cdmap(lane, rowm, colm);
  __syncthreads();

  const float s1v = s1g[hd * L_ + i0 + c0];
  const float av = __expf(s1v);          // exp(s1)
  const float cv = __expf(0.2f * s1v);   // exp(0.2*s1)
  const float th = __expf(-s1v);         // b >= th  <=>  s1+s2 >= 0
  const int qs = q * 8;

  // strength-reduced streams
  const float2*   bdp = bdg + (size_t)hd * L_ + jc * 1024 + qs;          // +32/kt
  const u16*      wp0 = WhTf + ((size_t)(hd * 4 + 0) * JW + jc * 32) * 512 + lane * 8;  // +512/kt
  const u16*      wp1 = WhTf + ((size_t)(hd * 4 + 1) * JW + jc * 32) * 512 + lane * 8;
  const u16*      wp2 = WhTf + ((size_t)(hd * 4 + 2) * JW + jc * 32) * 512 + lane * 8;
  const u16*      wp3 = WhTf + ((size_t)(hd * 4 + 3) * JW + jc * 32) * 512 + lane * 8;
  const unsigned* abp = &AbitL[c0][jc * 32];                              // +1/kt

  union PF { unsigned u[4]; short8 s; };
  floatx4 acc[4] = {};
  float dpart = 0.f;

  for (int kt = 0; kt < 32; ++kt) {
    float4 v0 = *(const float4*)bdp;
    float4 v1 = *(const float4*)(bdp + 2);
    float4 v2 = *(const float4*)(bdp + 4);
    float4 v3 = *(const float4*)(bdp + 6);
    short8 w0 = *(const short8*)wp0;
    short8 w1 = *(const short8*)wp1;
    short8 w2 = *(const short8*)wp2;
    short8 w3 = *(const short8*)wp3;
    const unsigned mb = (*abp >> qs) & 0xffu;

    // 8 j's: (b,d) = (v.x,v.y),(v.z,v.w) per float4
    float e0 = (v0.x >= th) ? (av * v0.x) : (cv * v0.y);
    float e1 = (v0.z >= th) ? (av * v0.z) : (cv * v0.w);
    float e2 = (v1.x >= th) ? (av * v1.x) : (cv * v1.y);
    float e3 = (v1.z >= th) ? (av * v1.z) : (cv * v1.w);
    float e4 = (v2.x >= th) ? (av * v2.x) : (cv * v2.y);
    float e5 = (v2.z >= th) ? (av * v2.z) : (cv * v2.w);
    float e6 = (v3.x >= th) ? (av * v3.x) : (cv * v3.y);
    float e7 = (v3.z >= th) ? (av * v3.z) : (cv * v3.w);
    e0 = (mb & 1u)   ? e0 : 0.f;
    e1 = (mb & 2u)   ? e1 : 0.f;
    e2 = (mb & 4u)   ? e2 : 0.f;
    e3 = (mb & 8u)   ? e3 : 0.f;
    e4 = (mb & 16u)  ? e4 : 0.f;
    e5 = (mb & 32u)  ? e5 : 0.f;
    e6 = (mb & 64u)  ? e6 : 0.f;
    e7 = (mb & 128u) ? e7 : 0.f;
    dpart += ((e0 + e1) + (e2 + e3)) + ((e4 + e5) + (e6 + e7));

    PF pf;
    pf.u[0] = cvt2(e0, e1); pf.u[1] = cvt2(e2, e3);
    pf.u[2] = cvt2(e4, e5); pf.u[3] = cvt2(e6, e7);
    acc[0] = __builtin_amdgcn_mfma_f32_16x16x32_bf16(pf.s, w0, acc[0], 0, 0, 0);
    acc[1] = __builtin_amdgcn_mfma_f32_16x16x32_bf16(pf.s, w1, acc[1], 0, 0, 0);
    acc[2] = __builtin_amdgcn_mfma_f32_16x16x32_bf16(pf.s, w2, acc[2], 0, 0, 0);
    acc[3] = __builtin_amdgcn_mfma_f32_16x16x32_bf16(pf.s, w3, acc[3], 0, 0, 0);

    bdp += 32; wp0 += 512; wp1 += 512; wp2 += 512; wp3 += 512; abp += 1;
  }

  // partial denom of row c0 over this j-chunk
  dpart += __shfl_xor(dpart, 16, 64);
  dpart += __shfl_xor(dpart, 32, 64);
  if (lane < 16) dden[hd][jc][lane] = dpart;

  auto writeT = [&](float (*P)[HD + 4]) {
    #pragma unroll
    for (int nt = 0; nt < 4; ++nt)
      #pragma unroll
      for (int r = 0; r < 4; ++r)
        P[rowm[r]][nt * 16 + colm[r]] = acc[nt][r];
  };
  auto addB2A = [&]() {
    const int h2 = t >> 8, rem = t & 255, row = rem >> 4, d4 = (rem & 15) * 4;
    float4* a = (float4*)&pA[h2][row][d4];
    float4 bv = *(float4*)&pB[h2][row][d4];
    float4 av2 = *a;
    av2.x += bv.x; av2.y += bv.y; av2.z += bv.z; av2.w += bv.w;
    *a = av2;
  };

  if (jc == 0) writeT(pA[hd]);
  if (jc == 1) writeT(pB[hd]);
  __syncthreads();
  if (t < 64) {
    const int hh = t >> 4, r = t & 15;
    float den = dden[hh][0][r] + dden[hh][1][r] + dden[hh][2][r] + dden[hh][3][r];
    rcpS[hh][r] = (den > 0.f) ? (1.f / den) : 0.f;  // empty row -> out = bias
  }
  addB2A();
  __syncthreads();
  if (jc == 2) writeT(pB[hd]);
  __syncthreads();
  addB2A();
  __syncthreads();
  if (jc == 3) writeT(pB[hd]);
  __syncthreads();
  addB2A();
  __syncthreads();

  {  // Cn (bf16)
    const int row = t >> 6, c4 = (t & 63) * 4;
    #pragma unroll
    for (int x = 0; x < 4; ++x) {
      const int col = c4 + x;
      const int hh = col >> 6, d = col & 63;
      CnL[row][col] = f2bf(pA[hh][row][d] * rcpS[hh][row]);
    }
  }
  __syncthreads();

  if (wv < 4) {  // projection: Out2(16x256) = Cn @ out_w.T
    const int cg = wv;
    floatx4 o[4] = {};
    #pragma unroll
    for (int kt = 0; kt < DOUT / 32; ++kt) {
      const int kb2 = kt * 32 + q * 8;
      short8 afr = *(const short8*)(&CnL[c0][kb2]);
      #pragma unroll
      for (int nt = 0; nt < 4; ++nt) {
        const int col = cg * 64 + nt * 16 + c0;
        short8 bfo = pack8(out_w + (size_t)col * DOUT + kb2);
        o[nt] = __builtin_amdgcn_mfma_f32_16x16x32_bf16(afr, bfo, o[nt], 0, 0, 0);
      }
    }
    #pragma unroll
    for (int nt = 0; nt < 4; ++nt)
      #pragma unroll
      for (int r = 0; r < 4; ++r) {
        const int col = cg * 64 + nt * 16 + colm[r];
        out[(size_t)(i0 + rowm[r]) * DOUT + col] = o[nt][r] + out_b[col];
      }
  }
}

// ---------------------------------------------------------------------------
extern "C" void kernel_launch(void* const* d_in, const int* in_sizes, int n_in,
                              void* d_out, int out_size, void* d_ws, size_t ws_size,
                              hipStream_t stream) {
  const float* h     = (const float*)d_in[0];   // (4096, 512) fp32
  const int*   A     = (const int*)d_in[1];     // (4096, 4096) int32
  const float* W     = (const float*)d_in[2];   // (256, 512) fp32
  const float* attn  = (const float*)d_in[3];   // (4, 128) fp32
  const float* out_w = (const float*)d_in[4];   // (256, 256) fp32
  const float* out_b = (const float*)d_in[5];   // (256,) fp32
  float* outp = (float*)d_out;                  // (4096, 256) fp32

  // ws: WhTf bf16 (2 MB) | s1 f32 (64 KB) | bd float2 (128 KB) | Abits (2 MB)
  const size_t WHTF_B  = (size_t)DOUT * L_ * 2;          // 2097152
  const size_t S1_B    = (size_t)NH * L_ * 4;            // 65536
  const size_t BD_B    = (size_t)NH * L_ * 8;            // 131072
  const size_t ABITS_B = (size_t)L_ * JW * 4;            // 2097152
  const size_t AB_OFF  = WHTF_B + S1_B + BD_B;

  u16*    WhTf = (u16*)d_ws;
  float*  s1g  = (float*)((char*)d_ws + WHTF_B);
  float2* bdg  = (float2*)((char*)d_ws + WHTF_B + S1_B);
  // Abits: prefer ws (known >= 8.55 MB from R7/R8 split runs); d_out fallback
  unsigned* Abits = (ws_size >= AB_OFF + ABITS_B)
                  ? (unsigned*)((char*)d_ws + AB_OFF)
                  : (unsigned*)((char*)d_out + 2097152);
  u16* Wf = (u16*)d_out;   // k_ab -> k1 -> k2 serialize; k2 overwrites d_out last

  hipLaunchKernelGGL(k_ab, dim3(2048), dim3(256), 0, stream, A, Abits, W, Wf);
  hipLaunchKernelGGL(k1_wh, dim3(L_ / 16), dim3(1024), 0, stream,
                     h, Wf, attn, WhTf, s1g, bdg);
  hipLaunchKernelGGL(k2_attn, dim3(L_ / 16), dim3(1024), 0, stream,
                     Abits, WhTf, s1g, bdg, out_w, out_b, outp);
}

// Round 10
// 153.692 us; speedup vs baseline: 1.2281x; 1.0330x over previous
//
#include <hip/hip_runtime.h>
#include <hip/hip_bf16.h>

#define L_    4096
#define DIN   512
#define DOUT  256
#define NH    4
#define HD    64
#define JW    128                      // L_/32 j-words per row

typedef unsigned short u16;
typedef __attribute__((ext_vector_type(8))) short short8;   // 8 x bf16
typedef __attribute__((ext_vector_type(4))) float floatx4;  // MFMA C/D frag

__device__ __forceinline__ float bf2f(u16 u) {
  union { unsigned u32; float f; } v; v.u32 = ((unsigned)u) << 16; return v.f;
}
__device__ __forceinline__ u16 f2bf(float f) {  // RNE
  union { float f; unsigned u; } v; v.f = f;
  unsigned r = v.u + 0x7fff + ((v.u >> 16) & 1);
  return (u16)(r >> 16);
}
__device__ __forceinline__ unsigned cvt2(float a, float b) {  // HW pack fp32x2->bf16x2
  __hip_bfloat162 v = __float22bfloat162_rn(make_float2(a, b));
  return *reinterpret_cast<unsigned*>(&v);
}
__device__ __forceinline__ short8 pack8(const float* __restrict__ p) {
  float4 a = *(const float4*)p, b = *(const float4*)(p + 4);
  union { unsigned u[4]; short8 s; } r;
  r.u[0] = cvt2(a.x, a.y); r.u[1] = cvt2(a.z, a.w);
  r.u[2] = cvt2(b.x, b.y); r.u[3] = cvt2(b.z, b.w);
  return r.s;
}

// C/D map discovery (r10-verified contract); layout-map-free probes.
__device__ __forceinline__ void mfma_cdmap(int lane, int* rowm, int* colm) {
  const int c0 = lane & 15;
  union { u16 u[8]; short8 s; } a1, b1, a2, b2;
  const u16 one = f2bf(1.f), cid = f2bf((float)c0);
  #pragma unroll
  for (int j = 0; j < 8; ++j) { a1.u[j] = cid; b1.u[j] = one; a2.u[j] = one; b2.u[j] = cid; }
  floatx4 z = {0.f, 0.f, 0.f, 0.f};
  floatx4 dr = __builtin_amdgcn_mfma_f32_16x16x32_bf16(a1.s, b1.s, z, 0, 0, 0);
  floatx4 dc = __builtin_amdgcn_mfma_f32_16x16x32_bf16(a2.s, b2.s, z, 0, 0, 0);
  #pragma unroll
  for (int r = 0; r < 4; ++r) {
    rowm[r] = (int)(dr[r] * 0.03125f + 0.5f);
    colm[r] = (int)(dc[r] * 0.03125f + 0.5f);
  }
}

// ---------------------------------------------------------------------------
// k_ab: A (64 MB) -> Abits (2 MB bitmask)  [all 2048 blocks]
//       + W -> Wf bf16 fragment pack       [blocks 0..15]   (R9-verified)
// ---------------------------------------------------------------------------
__global__ __launch_bounds__(256) void k_ab(const int* __restrict__ A,
                                            unsigned* __restrict__ Abits,
                                            const float* __restrict__ W,
                                            u16* __restrict__ Wf) {
  const int t = threadIdx.x;
  const int g = blockIdx.x * 256 + t;   // 524288 threads
  const int lane = t & 63;
  #pragma unroll
  for (int r = 0; r < 8; ++r) {
    const size_t gi = (size_t)r * 524288 + g;     // int4 index
    int4 v = *(const int4*)(A + gi * 4);
    unsigned nib = (v.x > 0 ? 1u : 0u) | (v.y > 0 ? 2u : 0u)
                 | (v.z > 0 ? 4u : 0u) | (v.w > 0 ? 8u : 0u);
    unsigned part = nib << ((lane & 7) * 4);
    part |= __shfl_xor(part, 1, 64);
    part |= __shfl_xor(part, 2, 64);
    part |= __shfl_xor(part, 4, 64);
    if ((lane & 7) == 0) Abits[gi >> 3] = part;
  }
  if (blockIdx.x < 16) {   // W pack (ex-k0b)
    const int col = g >> 4, kblock = g & 15;
    const int cg = col >> 6, nt = (col >> 4) & 3, c0 = col & 15;
    const float* src = W + (size_t)col * DIN + kblock * 32;
    u16* dst = Wf + ((size_t)(cg * 4 + nt) * 16 + kblock) * 512 + c0 * 8;
    #pragma unroll
    for (int q = 0; q < 4; ++q) {
      short8 v = pack8(src + q * 8);
      *(short8*)(dst + q * 128) = v;
    }
  }
}

// ---------------------------------------------------------------------------
// K1 (REWRITE): Wh = h @ W.T. 256 threads = 4 waves, wave = cg (64 cols),
// FULL K per wave in registers -> no K-split, no inter-wave reduction,
// no pA/pB phase dance. Barriers 11 -> 3. Fully-unrolled 16-step K loop
// gives 64 independent L2 loads of ILP per wave (1 wave/SIMD is enough).
// s1/s2 tail distributed over all 256 threads (16-iter partials + combine).
// Output contracts (WhTf chunk order, s1, bd=(exp(s2),exp(.2 s2))) are
// bit-identical to the verified k1.
// ---------------------------------------------------------------------------
__global__ __launch_bounds__(256) void k1_wh(
    const float* __restrict__ h, const u16* __restrict__ Wf,
    const float* __restrict__ attn,
    u16* __restrict__ WhTf, float* __restrict__ s1g, float2* __restrict__ bdg)
{
  const int i0 = blockIdx.x * 16;
  const int t = threadIdx.x;            // 256 threads = 4 waves
  const int wv = t >> 6, lane = t & 63, q = lane >> 4, c0 = lane & 15;
  const int cg = wv;                    // wave owns cols [cg*64, cg*64+64)
  int rowm[4], colm[4];
  mfma_cdmap(lane, rowm, colm);

  __shared__ u16  hT[16][DIN + 8];
  __shared__ float pA[16][DOUT + 8];
  __shared__ float attnL[NH * 128];
  __shared__ float s1p[4][64];
  __shared__ float s2p[4][64];

  attnL[t] = attn[t];
  attnL[t + 256] = attn[t + 256];
  #pragma unroll
  for (int rep = 0; rep < 4; ++rep) {   // stage h-tile coalesced (bf16)
    const int idx = rep * 256 + t;
    const int row = idx >> 6, c8 = (idx & 63) * 8;
    const float* hp = h + (size_t)(i0 + row) * DIN + c8;
    float4 a = *(const float4*)hp;
    float4 b = *(const float4*)(hp + 4);
    union { unsigned u[4]; int4 v; } pk;
    pk.u[0] = cvt2(a.x, a.y); pk.u[1] = cvt2(a.z, a.w);
    pk.u[2] = cvt2(b.x, b.y); pk.u[3] = cvt2(b.z, b.w);
    *(int4*)&hT[row][c8] = pk.v;
  }
  __syncthreads();

  floatx4 acc[4] = {};
  #pragma unroll
  for (int ks = 0; ks < 16; ++ks) {     // full K=512 in-registers
    const int kb = ks * 32 + q * 8;
    short8 af = *(const short8*)&hT[c0][kb];        // A[m=c0][k]
    #pragma unroll
    for (int nt = 0; nt < 4; ++nt) {
      short8 bf = *(const short8*)(Wf + ((size_t)(cg * 4 + nt) * 16 + ks) * 512 + lane * 8);
      acc[nt] = __builtin_amdgcn_mfma_f32_16x16x32_bf16(af, bf, acc[nt], 0, 0, 0);
    }
  }

  // Wh tile -> pA (each wave writes its own cg stripe; no overlap)
  #pragma unroll
  for (int nt = 0; nt < 4; ++nt)
    #pragma unroll
    for (int r = 0; r < 4; ++r)
      pA[rowm[r]][cg * 64 + nt * 16 + colm[r]] = acc[nt][r];
  __syncthreads();

  {  // s1/s2 partials: t = (qt, hh, r); 16 d's each
    const int r = t & 15, hh = (t >> 4) & 3, qt = t >> 6;
    float s1 = 0.f, s2 = 0.f;
    #pragma unroll
    for (int dd = 0; dd < 16; ++dd) {
      const int d = qt * 16 + dd;
      float v = pA[r][hh * 64 + d];
      s1 += v * attnL[hh * 128 + d];
      s2 += v * attnL[hh * 128 + 64 + d];
    }
    s1p[qt][hh * 16 + r] = s1;
    s2p[qt][hh * 16 + r] = s2;
  }
  __syncthreads();
  if (t < 64) {
    const int r = t & 15, hh = t >> 4;
    float s1 = s1p[0][t] + s1p[1][t] + s1p[2][t] + s1p[3][t];
    float s2 = s2p[0][t] + s2p[1][t] + s2p[2][t] + s2p[3][t];
    s1g[hh * L_ + i0 + r] = s1;
    bdg[hh * L_ + i0 + r] = make_float2(__expf(s2), __expf(0.2f * s2));
  }

  {  // WhTf store: thread t = d; two 16B writes (verified layout)
    const int d = t;
    const int hd = d >> 6, nt = (d >> 4) & 3, dc0 = d & 15;
    const int jblock = i0 >> 5, qbase = (i0 & 31) >> 3;
    u16* base = WhTf + ((size_t)(hd * 4 + nt) * JW + jblock) * 512 + dc0 * 8;
    #pragma unroll
    for (int jh = 0; jh < 2; ++jh) {
      const int i = jh * 8;
      union { unsigned u[4]; int4 v; } pk;
      pk.u[0] = cvt2(pA[i + 0][d], pA[i + 1][d]);
      pk.u[1] = cvt2(pA[i + 2][d], pA[i + 3][d]);
      pk.u[2] = cvt2(pA[i + 4][d], pA[i + 5][d]);
      pk.u[3] = cvt2(pA[i + 6][d], pA[i + 7][d]);
      *(int4*)(base + (qbase + jh) * 128) = pk.v;
    }
  }
}

// ---------------------------------------------------------------------------
// K2: masked softmax + PV + fused projection (R3-verified 49.0 us variant,
// restored verbatim: 2-kt software pipeline with named buffers, softmax
// hoisted to prefetch time, sched_barrier fences).
// ---------------------------------------------------------------------------
__global__ __launch_bounds__(1024) void k2_attn(
    const unsigned* __restrict__ Abits, const u16* __restrict__ WhTf,
    const float* __restrict__ s1g, const float2* __restrict__ bdg,
    const float* __restrict__ out_w, const float* __restrict__ out_b,
    float* __restrict__ out)
{
  const int i0 = blockIdx.x * 16;
  const int t = threadIdx.x;
  const int wv = t >> 6, lane = t & 63, q = lane >> 4, c0 = lane & 15;
  const int hd = wv & 3, jc = wv >> 2;

  __shared__ float pA[NH][16][HD + 4];
  __shared__ float pB[NH][16][HD + 4];
  __shared__ float dden[NH][4][16];
  __shared__ float rcpS[NH][16];
  __shared__ u16  CnL[16][DOUT + 8];
  __shared__ unsigned AbitL[16][JW + 2];   // row-stride 130 -> varied banks

  {  // prologue: stage this block's 16 rows of the bitmask (8 KB, coalesced)
    const int row = t >> 6, l = t & 63;
    uint2 w2 = *(const uint2*)&Abits[(size_t)(i0 + row) * JW + l * 2];
    AbitL[row][l * 2] = w2.x;
    AbitL[row][l * 2 + 1] = w2.y;
  }
  int rowm[4], colm[4];
  mfma_cdmap(lane, rowm, colm);
  __syncthreads();

  const float s1v = s1g[hd * L_ + i0 + c0];
  const float av = __expf(s1v);          // exp(s1)
  const float cv = __expf(0.2f * s1v);   // exp(0.2*s1)
  const float th = __expf(-s1v);         // b >= th  <=>  s1+s2 >= 0
  const float2* bdh = bdg + (size_t)hd * L_;
  const u16* Wc = WhTf + (size_t)(hd * 4) * JW * 512 + (size_t)(jc * 32) * 512 + lane * 8;
  const int jbase = jc * 1024;

  floatx4 acc[4] = {};
  float dpart = 0.f;

  union PF { unsigned u[4]; short8 s; };

  auto issueV = [&](int kt, float4* v) {
    const float2* p = bdh + jbase + kt * 32 + q * 8;
    v[0] = *(const float4*)p;       v[1] = *(const float4*)(p + 2);
    v[2] = *(const float4*)(p + 4); v[3] = *(const float4*)(p + 6);
  };
  auto issueW = [&](int kt, short8* w) {
    #pragma unroll
    for (int nt = 0; nt < 4; ++nt)
      w[nt] = *(const short8*)(Wc + ((size_t)nt * JW + kt) * 512);
  };
  auto sm8 = [&](const float4* v, int kt, PF& pf) {  // softmax -> bf16 A-frag
    const unsigned mb = (AbitL[c0][jc * 32 + kt] >> (q * 8)) & 0xffu;
    const float bb[8] = {v[0].x, v[0].z, v[1].x, v[1].z, v[2].x, v[2].z, v[3].x, v[3].z};
    const float dd[8] = {v[0].y, v[0].w, v[1].y, v[1].w, v[2].y, v[2].w, v[3].y, v[3].w};
    float ex[8];
    #pragma unroll
    for (int jj = 0; jj < 8; ++jj) {
      float p = (bb[jj] >= th) ? (av * bb[jj]) : (cv * dd[jj]);
      ex[jj] = ((mb >> jj) & 1u) ? p : 0.f;
      dpart += ex[jj];
    }
    pf.u[0] = cvt2(ex[0], ex[1]); pf.u[1] = cvt2(ex[2], ex[3]);
    pf.u[2] = cvt2(ex[4], ex[5]); pf.u[3] = cvt2(ex[6], ex[7]);
  };
  auto mfma4 = [&](PF& pf, const short8* w) {
    #pragma unroll
    for (int nt = 0; nt < 4; ++nt)
      acc[nt] = __builtin_amdgcn_mfma_f32_16x16x32_bf16(pf.s, w[nt], acc[nt], 0, 0, 0);
  };

  float4 vA[4], vB[4];
  short8 wA[4], wB[4];
  PF pfA, pfB;

  // prologue: fill both slots, pre-softmax slot A
  issueV(0, vA); issueW(0, wA);
  issueV(1, vB); issueW(1, wB);
  __builtin_amdgcn_sched_barrier(0);
  sm8(vA, 0, pfA);

  #pragma unroll 1
  for (int u = 0; u < 15; ++u) {
    const int kt = 2 * u;
    issueV(kt + 2, vA);                      // vA freed by sm8 last iter
    __builtin_amdgcn_sched_barrier(0);
    sm8(vB, kt + 1, pfB);                    // vB issued last iter (covered)
    mfma4(pfA, wA);                          // wA issued last iter (covered)
    __builtin_amdgcn_sched_barrier(0);
    issueW(kt + 2, wA);
    issueV(kt + 3, vB);
    __builtin_amdgcn_sched_barrier(0);
    mfma4(pfB, wB);                          // wB issued last iter (covered)
    __builtin_amdgcn_sched_barrier(0);
    issueW(kt + 3, wB);
    sm8(vA, kt + 2, pfA);                    // vA issued at loop top
    __builtin_amdgcn_sched_barrier(0);
  }
  // epilogue: pfA/wA hold kt=30, vB/wB hold kt=31
  mfma4(pfA, wA);
  sm8(vB, 31, pfB);
  mfma4(pfB, wB);

  // partial denom of row c0 over this j-chunk
  dpart += __shfl_xor(dpart, 16, 64);
  dpart += __shfl_xor(dpart, 32, 64);
  if (lane < 16) dden[hd][jc][lane] = dpart;

  auto writeT = [&](float (*P)[HD + 4]) {
    #pragma unroll
    for (int nt = 0; nt < 4; ++nt)
      #pragma unroll
      for (int r = 0; r < 4; ++r)
        P[rowm[r]][nt * 16 + colm[r]] = acc[nt][r];
  };
  auto addB2A = [&]() {
    const int h2 = t >> 8, rem = t & 255, row = rem >> 4, d4 = (rem & 15) * 4;
    float4* a = (float4*)&pA[h2][row][d4];
    float4 bv = *(float4*)&pB[h2][row][d4];
    float4 av2 = *a;
    av2.x += bv.x; av2.y += bv.y; av2.z += bv.z; av2.w += bv.w;
    *a = av2;
  };

  if (jc == 0) writeT(pA[hd]);
  if (jc == 1) writeT(pB[hd]);
  __syncthreads();
  if (t < 64) {
    const int hh = t >> 4, r = t & 15;
    float den = dden[hh][0][r] + dden[hh][1][r] + dden[hh][2][r] + dden[hh][3][r];
    rcpS[hh][r] = (den > 0.f) ? (1.f / den) : 0.f;  // empty row -> out = bias
  }
  addB2A();
  __syncthreads();
  if (jc == 2) writeT(pB[hd]);
  __syncthreads();
  addB2A();
  __syncthreads();
  if (jc == 3) writeT(pB[hd]);
  __syncthreads();
  addB2A();
  __syncthreads();

  {  // Cn (bf16)
    const int row = t >> 6, c4 = (t & 63) * 4;
    #pragma unroll
    for (int x = 0; x < 4; ++x) {
      const int col = c4 + x;
      const int hh = col >> 6, d = col & 63;
      CnL[row][col] = f2bf(pA[hh][row][d] * rcpS[hh][row]);
    }
  }
  __syncthreads();

  if (wv < 4) {  // projection: Out2(16x256) = Cn @ out_w.T
    const int cg = wv;
    floatx4 o[4] = {};
    #pragma unroll
    for (int kt = 0; kt < DOUT / 32; ++kt) {
      const int kb2 = kt * 32 + q * 8;
      short8 afr = *(const short8*)(&CnL[c0][kb2]);
      #pragma unroll
      for (int nt = 0; nt < 4; ++nt) {
        const int col = cg * 64 + nt * 16 + c0;
        short8 bfo = pack8(out_w + (size_t)col * DOUT + kb2);
        o[nt] = __builtin_amdgcn_mfma_f32_16x16x32_bf16(afr, bfo, o[nt], 0, 0, 0);
      }
    }
    #pragma unroll
    for (int nt = 0; nt < 4; ++nt)
      #pragma unroll
      for (int r = 0; r < 4; ++r) {
        const int col = cg * 64 + nt * 16 + colm[r];
        out[(size_t)(i0 + rowm[r]) * DOUT + col] = o[nt][r] + out_b[col];
      }
  }
}

// ---------------------------------------------------------------------------
extern "C" void kernel_launch(void* const* d_in, const int* in_sizes, int n_in,
                              void* d_out, int out_size, void* d_ws, size_t ws_size,
                              hipStream_t stream) {
  const float* h     = (const float*)d_in[0];   // (4096, 512) fp32
  const int*   A     = (const int*)d_in[1];     // (4096, 4096) int32
  const float* W     = (const float*)d_in[2];   // (256, 512) fp32
  const float* attn  = (const float*)d_in[3];   // (4, 128) fp32
  const float* out_w = (const float*)d_in[4];   // (256, 256) fp32
  const float* out_b = (const float*)d_in[5];   // (256,) fp32
  float* outp = (float*)d_out;                  // (4096, 256) fp32

  // ws: WhTf bf16 (2 MB) | s1 f32 (64 KB) | bd float2 (128 KB) | Abits (2 MB)
  const size_t WHTF_B  = (size_t)DOUT * L_ * 2;          // 2097152
  const size_t S1_B    = (size_t)NH * L_ * 4;            // 65536
  const size_t BD_B    = (size_t)NH * L_ * 8;            // 131072
  const size_t ABITS_B = (size_t)L_ * JW * 4;            // 2097152
  const size_t AB_OFF  = WHTF_B + S1_B + BD_B;

  u16*    WhTf = (u16*)d_ws;
  float*  s1g  = (float*)((char*)d_ws + WHTF_B);
  float2* bdg  = (float2*)((char*)d_ws + WHTF_B + S1_B);
  // Abits: prefer ws; fall back to the second 2 MB of d_out
  unsigned* Abits = (ws_size >= AB_OFF + ABITS_B)
                  ? (unsigned*)((char*)d_ws + AB_OFF)
                  : (unsigned*)((char*)d_out + 2097152);
  u16* Wf = (u16*)d_out;   // k_ab -> k1 -> k2 serialize; k2 overwrites d_out last

  hipLaunchKernelGGL(k_ab, dim3(2048), dim3(256), 0, stream, A, Abits, W, Wf);
  hipLaunchKernelGGL(k1_wh, dim3(L_ / 16), dim3(256), 0, stream,
                     h, Wf, attn, WhTf, s1g, bdg);
  hipLaunchKernelGGL(k2_attn, dim3(L_ / 16), dim3(1024), 0, stream,
                     Abits, WhTf, s1g, bdg, out_w, out_b, outp);
}